// Round 2
// baseline (131.808 us; speedup 1.0000x reference)
//
#include <hip/hip_runtime.h>
#include <stdint.h>

// Lovasz-softmax loss, B=4 C=19 H=W=512, P=1M pixels.
// R6: 4 px/thread float4-vectorized (256 blocks = exact 1-block/CU cover,
// half the load insts vs R4, half the partials -> reduce traffic halved),
// 2-way lane-replicated STATIC LDS sub-histograms (addr = bin*2 + (tid&1),
// 77.8 KB) to cut intra-wave same-address ds_add_u64 serialization ~2x.
// No dynamic LDS, no host-side attribute calls (graph-capture safe).
// 3 dispatches.

#define IGNORE_LBL 255
typedef unsigned long long u64;
constexpr int C_CLS = 19;
constexpr int NB = 256;                 // bins per class
constexpr int NBT = C_CLS * NB;         // 4864
constexpr int HREP = 2;                 // lane-replicated histogram copies
constexpr int HW_C = 512 * 512;         // per-batch pixel count
constexpr int HIST_GRID = 256;
constexpr int HIST_NT = 1024;
constexpr int PX = 4;                   // pixels per thread
constexpr int RED_Q = 8;                // reduction segments (256/8 = 32 each)
constexpr float ESCALE = 262144.f;      // 2^18 fixed-point scale

// Geometric binning of e in [0,1]:
//   bin 0       : e < 2^-7
//   E=120..126  : 2^(E-119) buckets each (width 2^-8)
//   bin 255     : e >= 1.0
// Monotone in e; max bucket width 2^-7 (bin 0 only).
__device__ __forceinline__ int err_bin(float e) {
    unsigned u = __float_as_uint(e);
    if (u >= 0x3F800000u) return NB - 1;
    if (u < 0x3C000000u) return 0;
    int m = (int)(u >> 23) - 119;                       // 1..7
    return (1 << m) - 1 + (int)((u & 0x7FFFFFu) >> (23 - m));
}

__global__ __launch_bounds__(HIST_NT)
void lovasz_hist_kernel(const float* __restrict__ logits,
                        const int* __restrict__ gt,
                        u64* __restrict__ part) {
    __shared__ u64 h[NBT * HREP];       // 77,824 B; esum[0:31]|cnt[32:45]|fg[46:63]
    for (int i = threadIdx.x; i < NBT * HREP; i += HIST_NT) h[i] = 0ull;
    __syncthreads();

    // exact cover: 256 blocks * 1024 threads * 4 px = 1,048,576
    const int gid = blockIdx.x * HIST_NT + threadIdx.x;
    const int p0 = gid * PX;
    const int b = p0 >> 18;             // p0 / HW_C (4-aligned, same batch)
    const int hw = p0 & (HW_C - 1);
    const float4* base =
        (const float4*)(logits + (size_t)b * C_CLS * HW_C + hw);

    float4 v[C_CLS];
    float mx0 = -3.4e38f, mx1 = -3.4e38f, mx2 = -3.4e38f, mx3 = -3.4e38f;
#pragma unroll
    for (int c = 0; c < C_CLS; ++c) {
        v[c] = base[(size_t)c * (HW_C / 4)];
        mx0 = fmaxf(mx0, v[c].x);
        mx1 = fmaxf(mx1, v[c].y);
        mx2 = fmaxf(mx2, v[c].z);
        mx3 = fmaxf(mx3, v[c].w);
    }
    float s0 = 0.f, s1 = 0.f, s2 = 0.f, s3 = 0.f;
#pragma unroll
    for (int c = 0; c < C_CLS; ++c) {
        v[c].x = __expf(v[c].x - mx0);
        v[c].y = __expf(v[c].y - mx1);
        v[c].z = __expf(v[c].z - mx2);
        v[c].w = __expf(v[c].w - mx3);
        s0 += v[c].x;
        s1 += v[c].y;
        s2 += v[c].z;
        s3 += v[c].w;
    }
    const float inv0 = 1.0f / s0;
    const float inv1 = 1.0f / s1;
    const float inv2 = 1.0f / s2;
    const float inv3 = 1.0f / s3;

    const int4 lbl = *(const int4*)(gt + p0);
    const bool val0 = (lbl.x != IGNORE_LBL);
    const bool val1 = (lbl.y != IGNORE_LBL);
    const bool val2 = (lbl.z != IGNORE_LBL);
    const bool val3 = (lbl.w != IGNORE_LBL);

    const unsigned rep = threadIdx.x & (HREP - 1);

#define UPD(PV, INVV, LBV, VALV)                                              \
    if (VALV) {                                                               \
        float prob = (PV) * (INVV);                                           \
        bool fg = (c == (LBV));                                               \
        float e = fmaxf(fg ? (1.0f - prob) : prob, 0.0f);                     \
        unsigned eq = __float2uint_rn(e * ESCALE);                            \
        u64 add = (u64)eq | (1ull << 32) | (fg ? (1ull << 46) : 0ull);        \
        atomicAdd(&h[((unsigned)(c * NB + err_bin(e)) << 1) | rep], add);     \
    }

#pragma unroll
    for (int c = 0; c < C_CLS; ++c) {
        UPD(v[c].x, inv0, lbl.x, val0)
        UPD(v[c].y, inv1, lbl.y, val1)
        UPD(v[c].z, inv2, lbl.z, val2)
        UPD(v[c].w, inv3, lbl.w, val3)
    }
#undef UPD
    __syncthreads();

    // merge the 2 replicas and write this block's partial
    const size_t base_out = (size_t)blockIdx.x * NBT;
    for (int i = threadIdx.x; i < NBT; i += HIST_NT) {
        const int j = i << 1;
        part[base_out + i] = h[j] + h[j + 1];
    }
}

// Fold 256 partials -> RED_Q per bin. grid = RED_Q * 19 blocks of 256 thr.
// Block 0 also zeroes the final-accumulator words (runs before scan).
__global__ __launch_bounds__(256)
void lovasz_reduce_kernel(const u64* __restrict__ part,
                          u64* __restrict__ red_es,
                          u64* __restrict__ red_cf,
                          unsigned* __restrict__ acc) {
    if (blockIdx.x == 0 && threadIdx.x < 4) acc[threadIdx.x] = 0u;
    const int q = blockIdx.x / C_CLS;            // 0..RED_Q-1
    const int seg = blockIdx.x % C_CLS;
    const int bin = seg * NB + threadIdx.x;      // 0..NBT-1
    const int p0 = q * (HIST_GRID / RED_Q);
    u64 es = 0; unsigned cn = 0, fgc = 0;
#pragma unroll 4
    for (int p = p0; p < p0 + HIST_GRID / RED_Q; ++p) {
        u64 x = part[(size_t)p * NBT + bin];
        es += x & 0xFFFFFFFFull;
        cn += (unsigned)((x >> 32) & 0x3FFFu);
        fgc += (unsigned)(x >> 46);
    }
    red_es[(size_t)q * NBT + bin] = es;
    red_cf[(size_t)q * NBT + bin] = (u64)cn | ((u64)fgc << 32);
}

// One block per class: fold RED_Q, single-chunk descending scan, and the
// last class block writes the final averaged loss (device-scope atomics).
__global__ __launch_bounds__(NB)
void lovasz_scan_kernel(const u64* __restrict__ red_es,
                        const u64* __restrict__ red_cf,
                        float* __restrict__ loss_acc,    // acc[0]
                        int* __restrict__ pres_acc,      // acc[1]
                        unsigned* __restrict__ done_ctr, // acc[2]
                        float* __restrict__ out) {
    const int c = blockIdx.x;
    const int t = threadIdx.x;                   // 0..255
    const int lane = t & 63;
    const int wave = t >> 6;                     // 4 waves

    __shared__ u64 wtot[4];
    __shared__ u64 sh_total;

    // ---- Phase 0: fold the RED_Q reduced partials (descending bin order) ----
    const int db = NB - 1 - t;
    const size_t bo = (size_t)c * NB + db;
    u64 es = 0, nf = 0;                          // nf = cnt | fg<<32
#pragma unroll
    for (int q = 0; q < RED_Q; ++q) {
        es += red_es[(size_t)q * NBT + bo];
        nf += red_cf[(size_t)q * NBT + bo];
    }
    const double mys = (double)es * (1.0 / (double)ESCALE);

    // ---- Phase 1: inclusive scan over the 256 descending bins ----
    u64 incl = nf;
#pragma unroll
    for (int o = 1; o < 64; o <<= 1) {
        u64 u = __shfl_up(incl, o, 64);
        if (lane >= o) incl += u;
    }
    if (lane == 63) wtot[wave] = incl;
    __syncthreads();
    if (t == 0) {
        u64 run = 0;
#pragma unroll
        for (int w = 0; w < 4; ++w) { u64 x = wtot[w]; wtot[w] = run; run += x; }
        sh_total = run;
    }
    __syncthreads();

    const long long G = (long long)(sh_total >> 32);
    const u64 excl = wtot[wave] + (incl - nf);

    double lsum = 0.0;
    {
        long long n_b = (long long)(nf & 0xffffffffull);
        if (n_b > 0 && G > 0) {
            long long f_b = (long long)(nf >> 32);
            long long k0 = (long long)(excl & 0xffffffffull);
            long long F0 = (long long)(excl >> 32);
            long long I0 = G - F0;
            long long U0 = G + k0 - F0;
            long long F1 = F0 + f_b;
            long long I1 = G - F1;
            long long U1 = G + (k0 + n_b) - F1;
            // dJ = I0/U0 - I1/U1 exactly (int64 cross product, <= 2^41)
            double dJ = (double)(I0 * U1 - I1 * U0) / ((double)U0 * (double)U1);
            lsum = (mys / (double)n_b) * dJ;
        }
    }

    // ---- block reduce (double, 4 waves) ----
    __shared__ double dred[4];
#pragma unroll
    for (int o = 32; o > 0; o >>= 1) lsum += __shfl_down(lsum, o, 64);
    if (lane == 0) dred[wave] = lsum;
    __syncthreads();
    if (t == 0) {
        double tot = dred[0] + dred[1] + dred[2] + dred[3];
        if (G > 0) {
            atomicAdd(loss_acc, (float)tot);
            atomicAdd(pres_acc, 1);
        }
        __threadfence();
        unsigned d = atomicAdd(done_ctr, 1u);
        if (d == C_CLS - 1) {                    // last class block
            float lv = atomicAdd(loss_acc, 0.0f);
            int pv = atomicAdd(pres_acc, 0);
            out[0] = lv / fmaxf((float)pv, 1.0f);
        }
    }
}

extern "C" void kernel_launch(void* const* d_in, const int* in_sizes, int n_in,
                              void* d_out, int out_size, void* d_ws, size_t ws_size,
                              hipStream_t stream) {
    const float* logits = (const float*)d_in[0];
    const int* gt = (const int*)d_in[1];
    float* out = (float*)d_out;

    // workspace layout (all fully overwritten each call; no memset needed)
    size_t partBytes = (size_t)HIST_GRID * NBT * sizeof(u64);       // 9.96 MB
    size_t partPad = (partBytes + 255) & ~(size_t)255;
    size_t redBytes = (size_t)RED_Q * NBT * sizeof(u64);            // 311 KB
    size_t redPad = (redBytes + 255) & ~(size_t)255;
    u64* part = (u64*)d_ws;
    u64* red_es = (u64*)((char*)d_ws + partPad);
    u64* red_cf = (u64*)((char*)d_ws + partPad + redPad);
    unsigned* acc = (unsigned*)((char*)d_ws + partPad + 2 * redPad);
    float* loss_acc = (float*)&acc[0];
    int* pres_acc = (int*)&acc[1];
    unsigned* done_ctr = &acc[2];

    lovasz_hist_kernel<<<HIST_GRID, HIST_NT, 0, stream>>>(logits, gt, part);
    lovasz_reduce_kernel<<<RED_Q * C_CLS, 256, 0, stream>>>(part, red_es, red_cf, acc);
    lovasz_scan_kernel<<<C_CLS, NB, 0, stream>>>(red_es, red_cf,
                                                 loss_acc, pres_acc, done_ctr, out);
}

// Round 3
// 131.268 us; speedup vs baseline: 1.0041x; 1.0041x over previous
//
#include <hip/hip_runtime.h>
#include <stdint.h>

// Lovasz-softmax loss, B=4 C=19 H=W=512, P=1M pixels.
// R7: NB=128 geometric bins (ordering-only approximation; esum stays exact
// 2^-18 fixed point, so binning error is second-order — measured absmax was
// 0.0 at NB=256), which lets HREP=4 lane-replicated LDS sub-histograms fit
// in 77.8 KB (4x fewer intra-wave same-address ds_add_u64 collisions at the
// same occupancy as R6). Additionally skip non-fg updates with e < 2^-6
// (bin 0 = last bin of the descending scan where grad ~ 0): removes ~23% of
// atomics including the hottest address. 2 px/thread float2 (low VGPR).
// 3 dispatches.

#define IGNORE_LBL 255
typedef unsigned long long u64;
constexpr int C_CLS = 19;
constexpr int NB = 128;                 // bins per class
constexpr int NBT = C_CLS * NB;         // 2432
constexpr int HREP = 4;                 // lane-replicated histogram copies
constexpr int HW_C = 512 * 512;         // per-batch pixel count
constexpr int HIST_GRID = 512;
constexpr int HIST_NT = 1024;
constexpr int PX = 2;                   // pixels per thread
constexpr int RED_Q = 8;                // reduction segments (512/8 = 64 each)
constexpr float ESCALE = 262144.f;      // 2^18 fixed-point scale
constexpr float E_SKIP = 0.015625f;     // 2^-6: bin-0 threshold

// Geometric binning of e in [0,1] into 128 bins:
//   bin 0       : e < 2^-6
//   E=121..126  : 2^(E-120) buckets each (width >= 2^-7)
//   bin 127     : e >= 1.0
// Monotone in e.
__device__ __forceinline__ int err_bin(float e) {
    unsigned u = __float_as_uint(e);
    if (u >= 0x3F800000u) return NB - 1;
    if (u < 0x3D800000u) return 0;
    int m = (int)(u >> 23) - 120;                       // 1..6
    return (1 << m) - 1 + (int)((u & 0x7FFFFFu) >> (23 - m));
}

__global__ __launch_bounds__(HIST_NT)
void lovasz_hist_kernel(const float* __restrict__ logits,
                        const int* __restrict__ gt,
                        u64* __restrict__ part) {
    __shared__ u64 h[NBT * HREP];       // 77,824 B; esum[0:31]|cnt[32:45]|fg[46:63]
    for (int i = threadIdx.x; i < NBT * HREP; i += HIST_NT) h[i] = 0ull;
    __syncthreads();

    // exact cover: 512 blocks * 1024 threads * 2 px = 1,048,576
    const int gid = blockIdx.x * HIST_NT + threadIdx.x;
    const int p0 = gid * PX;
    const int b = p0 >> 18;             // p0 / HW_C (2-aligned, same batch)
    const int hw = p0 & (HW_C - 1);
    const float2* base =
        (const float2*)(logits + (size_t)b * C_CLS * HW_C + hw);

    float2 v[C_CLS];
    float mx0 = -3.4e38f, mx1 = -3.4e38f;
#pragma unroll
    for (int c = 0; c < C_CLS; ++c) {
        v[c] = base[(size_t)c * (HW_C / 2)];
        mx0 = fmaxf(mx0, v[c].x);
        mx1 = fmaxf(mx1, v[c].y);
    }
    float s0 = 0.f, s1 = 0.f;
#pragma unroll
    for (int c = 0; c < C_CLS; ++c) {
        v[c].x = __expf(v[c].x - mx0);
        v[c].y = __expf(v[c].y - mx1);
        s0 += v[c].x;
        s1 += v[c].y;
    }
    const float inv0 = 1.0f / s0;
    const float inv1 = 1.0f / s1;

    const int2 lbl2 = *(const int2*)(gt + p0);
    const bool val0 = (lbl2.x != IGNORE_LBL);
    const bool val1 = (lbl2.y != IGNORE_LBL);

    const unsigned rep = threadIdx.x & (HREP - 1);

#define UPD(PV, INVV, LBV, VALV)                                              \
    if (VALV) {                                                               \
        float prob = (PV) * (INVV);                                           \
        bool fg = (c == (LBV));                                               \
        float e = fmaxf(fg ? (1.0f - prob) : prob, 0.0f);                     \
        if (fg || e >= E_SKIP) {                                              \
            unsigned eq = __float2uint_rn(e * ESCALE);                        \
            u64 add = (u64)eq | (1ull << 32) | (fg ? (1ull << 46) : 0ull);    \
            atomicAdd(&h[((unsigned)(c * NB + err_bin(e)) << 2) | rep], add); \
        }                                                                     \
    }

#pragma unroll
    for (int c = 0; c < C_CLS; ++c) {
        UPD(v[c].x, inv0, lbl2.x, val0)
        UPD(v[c].y, inv1, lbl2.y, val1)
    }
#undef UPD
    __syncthreads();

    // merge the 4 replicas and write this block's partial
    const size_t base_out = (size_t)blockIdx.x * NBT;
    for (int i = threadIdx.x; i < NBT; i += HIST_NT) {
        const int j = i << 2;
        part[base_out + i] = h[j] + h[j + 1] + h[j + 2] + h[j + 3];
    }
}

// Fold 512 partials -> RED_Q per bin. grid = RED_Q * 19 blocks of NB thr.
// Block 0 also zeroes the final-accumulator words (runs before scan).
__global__ __launch_bounds__(NB)
void lovasz_reduce_kernel(const u64* __restrict__ part,
                          u64* __restrict__ red_es,
                          u64* __restrict__ red_cf,
                          unsigned* __restrict__ acc) {
    if (blockIdx.x == 0 && threadIdx.x < 4) acc[threadIdx.x] = 0u;
    const int q = blockIdx.x / C_CLS;            // 0..RED_Q-1
    const int seg = blockIdx.x % C_CLS;
    const int bin = seg * NB + threadIdx.x;      // 0..NBT-1
    const int p0 = q * (HIST_GRID / RED_Q);
    u64 es = 0; unsigned cn = 0, fgc = 0;
#pragma unroll 4
    for (int p = p0; p < p0 + HIST_GRID / RED_Q; ++p) {
        u64 x = part[(size_t)p * NBT + bin];
        es += x & 0xFFFFFFFFull;
        cn += (unsigned)((x >> 32) & 0x3FFFu);
        fgc += (unsigned)(x >> 46);
    }
    red_es[(size_t)q * NBT + bin] = es;
    red_cf[(size_t)q * NBT + bin] = (u64)cn | ((u64)fgc << 32);
}

// One block per class: fold RED_Q, single-chunk descending scan, and the
// last class block writes the final averaged loss (device-scope atomics).
__global__ __launch_bounds__(NB)
void lovasz_scan_kernel(const u64* __restrict__ red_es,
                        const u64* __restrict__ red_cf,
                        float* __restrict__ loss_acc,    // acc[0]
                        int* __restrict__ pres_acc,      // acc[1]
                        unsigned* __restrict__ done_ctr, // acc[2]
                        float* __restrict__ out) {
    const int c = blockIdx.x;
    const int t = threadIdx.x;                   // 0..127
    const int lane = t & 63;
    const int wave = t >> 6;                     // 2 waves

    __shared__ u64 wtot[2];
    __shared__ u64 sh_total;

    // ---- Phase 0: fold the RED_Q reduced partials (descending bin order) ----
    const int db = NB - 1 - t;
    const size_t bo = (size_t)c * NB + db;
    u64 es = 0, nf = 0;                          // nf = cnt | fg<<32
#pragma unroll
    for (int q = 0; q < RED_Q; ++q) {
        es += red_es[(size_t)q * NBT + bo];
        nf += red_cf[(size_t)q * NBT + bo];
    }
    const double mys = (double)es * (1.0 / (double)ESCALE);

    // ---- Phase 1: inclusive scan over the 128 descending bins ----
    u64 incl = nf;
#pragma unroll
    for (int o = 1; o < 64; o <<= 1) {
        u64 u = __shfl_up(incl, o, 64);
        if (lane >= o) incl += u;
    }
    if (lane == 63) wtot[wave] = incl;
    __syncthreads();
    if (t == 0) {
        u64 run = 0;
#pragma unroll
        for (int w = 0; w < 2; ++w) { u64 x = wtot[w]; wtot[w] = run; run += x; }
        sh_total = run;
    }
    __syncthreads();

    const long long G = (long long)(sh_total >> 32);
    const u64 excl = wtot[wave] + (incl - nf);

    double lsum = 0.0;
    {
        long long n_b = (long long)(nf & 0xffffffffull);
        if (n_b > 0 && G > 0) {
            long long f_b = (long long)(nf >> 32);
            long long k0 = (long long)(excl & 0xffffffffull);
            long long F0 = (long long)(excl >> 32);
            long long I0 = G - F0;
            long long U0 = G + k0 - F0;
            long long F1 = F0 + f_b;
            long long I1 = G - F1;
            long long U1 = G + (k0 + n_b) - F1;
            // dJ = I0/U0 - I1/U1 exactly (int64 cross product, <= 2^41)
            double dJ = (double)(I0 * U1 - I1 * U0) / ((double)U0 * (double)U1);
            lsum = (mys / (double)n_b) * dJ;
        }
    }

    // ---- block reduce (double, 2 waves) ----
    __shared__ double dred[2];
#pragma unroll
    for (int o = 32; o > 0; o >>= 1) lsum += __shfl_down(lsum, o, 64);
    if (lane == 0) dred[wave] = lsum;
    __syncthreads();
    if (t == 0) {
        double tot = dred[0] + dred[1];
        if (G > 0) {
            atomicAdd(loss_acc, (float)tot);
            atomicAdd(pres_acc, 1);
        }
        __threadfence();
        unsigned d = atomicAdd(done_ctr, 1u);
        if (d == C_CLS - 1) {                    // last class block
            float lv = atomicAdd(loss_acc, 0.0f);
            int pv = atomicAdd(pres_acc, 0);
            out[0] = lv / fmaxf((float)pv, 1.0f);
        }
    }
}

extern "C" void kernel_launch(void* const* d_in, const int* in_sizes, int n_in,
                              void* d_out, int out_size, void* d_ws, size_t ws_size,
                              hipStream_t stream) {
    const float* logits = (const float*)d_in[0];
    const int* gt = (const int*)d_in[1];
    float* out = (float*)d_out;

    // workspace layout (all fully overwritten each call; no memset needed)
    size_t partBytes = (size_t)HIST_GRID * NBT * sizeof(u64);       // 9.96 MB
    size_t partPad = (partBytes + 255) & ~(size_t)255;
    size_t redBytes = (size_t)RED_Q * NBT * sizeof(u64);            // 156 KB
    size_t redPad = (redBytes + 255) & ~(size_t)255;
    u64* part = (u64*)d_ws;
    u64* red_es = (u64*)((char*)d_ws + partPad);
    u64* red_cf = (u64*)((char*)d_ws + partPad + redPad);
    unsigned* acc = (unsigned*)((char*)d_ws + partPad + 2 * redPad);
    float* loss_acc = (float*)&acc[0];
    int* pres_acc = (int*)&acc[1];
    unsigned* done_ctr = &acc[2];

    lovasz_hist_kernel<<<HIST_GRID, HIST_NT, 0, stream>>>(logits, gt, part);
    lovasz_reduce_kernel<<<RED_Q * C_CLS, NB, 0, stream>>>(part, red_es, red_cf, acc);
    lovasz_scan_kernel<<<C_CLS, NB, 0, stream>>>(red_es, red_cf,
                                                 loss_acc, pres_acc, done_ctr, out);
}